// Round 10
// baseline (253.974 us; speedup 1.0000x reference)
//
#include <hip/hip_runtime.h>
#include <hip/hip_bf16.h>

#define D 64
#define RSHIFT 9             // 512 nodes per dst-bucket
#define BNODES 512
#define MAXB 256             // >= nb = ceil(100000/512) = 196
#define BCAP 10240           // per-bucket edge capacity (mean 8192, sigma ~90)
#define SCAP 14336           // per-bucket PADDED ssrc capacity
#define FH 72                // LDS row stride (bf16): 144B, 4-bank skew per row

typedef unsigned short ushort_t;
typedef unsigned int uint_t;
typedef short short8 __attribute__((ext_vector_type(8)));   // 8 bf16 MFMA frag
typedef float floatx4 __attribute__((ext_vector_type(4)));  // MFMA C/D frag

__device__ inline uint_t pk_bf16(float x, float y) {
    uint_t ux = __float_as_uint(x); ux = ux + 0x7fffu + ((ux >> 16) & 1u);
    uint_t uy = __float_as_uint(y); uy = uy + 0x7fffu + ((uy >> 16) & 1u);
    return (ux >> 16) | (uy & 0xffff0000u);
}
__device__ inline ushort_t rnd_bf16(float x) {
    uint_t u = __float_as_uint(x); u = u + 0x7fffu + ((u >> 16) & 1u);
    return (ushort_t)(u >> 16);
}

// ---------------- stage 1: bucket edges by dst range ----------------
// Packed entry: (src << 9) | (dst & 511). LDS atomics only.
__global__ __launch_bounds__(256) void k_bucket(const int* __restrict__ src,
                                                const int* __restrict__ dst,
                                                int* __restrict__ bcur,
                                                int* __restrict__ ebuf,
                                                int E, int nb) {
    __shared__ int lcnt[MAXB];
    __shared__ int lbase[MAXB];
    int t = threadIdx.x;
    lcnt[t] = 0;
    __syncthreads();
    int base = blockIdx.x * 2048 + t * 8;
    int sv[8], dv[8], sl[8];
    if (base + 7 < E) {
        int4 a0 = *(const int4*)(src + base);
        int4 a1 = *(const int4*)(src + base + 4);
        int4 b0 = *(const int4*)(dst + base);
        int4 b1 = *(const int4*)(dst + base + 4);
        sv[0]=a0.x; sv[1]=a0.y; sv[2]=a0.z; sv[3]=a0.w;
        sv[4]=a1.x; sv[5]=a1.y; sv[6]=a1.z; sv[7]=a1.w;
        dv[0]=b0.x; dv[1]=b0.y; dv[2]=b0.z; dv[3]=b0.w;
        dv[4]=b1.x; dv[5]=b1.y; dv[6]=b1.z; dv[7]=b1.w;
    } else {
        #pragma unroll
        for (int j = 0; j < 8; ++j) {
            dv[j] = (base + j < E) ? dst[base + j] : -1;
            sv[j] = (base + j < E) ? src[base + j] : 0;
        }
    }
    #pragma unroll
    for (int j = 0; j < 8; ++j) {
        if (dv[j] >= 0) {
            int b = dv[j] >> RSHIFT;
            sl[j] = atomicAdd(&lcnt[b], 1);   // LDS atomic only
        }
    }
    __syncthreads();
    if (t < nb) { int c = lcnt[t]; if (c) lbase[t] = atomicAdd(&bcur[t], c); }
    __syncthreads();
    #pragma unroll
    for (int j = 0; j < 8; ++j) {
        if (dv[j] >= 0) {
            int b = dv[j] >> RSHIFT;
            int slot = lbase[b] + sl[j];
            if (slot < BCAP)
                ebuf[(size_t)b * BCAP + slot] = (sv[j] << RSHIFT) | (dv[j] & (BNODES - 1));
        }
    }
}

// ---------------- stage 2: per-bucket CSR build, all atomics in LDS -------
// R10 addition: in-LDS degree counting-sort of the bucket's 512 nodes ->
// nperm (slot -> node). Tiles of 64 consecutive slots are degree-similar:
// kills within-wave lockstep divergence (max-of-8 n8 -> ~mean) and the
// fagg barrier tail (max-of-64 -> ~mean). MFMA tiles are permutation-
// invariant, so any 64 nodes can share a tile.
__global__ __launch_bounds__(256) void k_csr(const int* __restrict__ ebuf,
                                             const int* __restrict__ bcur,
                                             int2* __restrict__ rowse,
                                             int* __restrict__ ssrc,
                                             float* __restrict__ dis,
                                             int* __restrict__ nperm,
                                             int N, int nb) {
    __shared__ int sseg[BCAP];        // 40 KB edge stage
    __shared__ int lcnt[BNODES];
    __shared__ int lcur[BNODES];
    __shared__ int sums[256];
    __shared__ int chist[33];
    int b = blockIdx.x;
    int t = threadIdx.x;
    int n = bcur[b];
    if (n > BCAP) n = BCAP;
    int node0 = b << RSHIFT;
    #pragma unroll
    for (int i = t; i < BNODES; i += 256) lcnt[i] = 0;
    __syncthreads();
    const int* seg = ebuf + (size_t)b * BCAP;
    for (int i = t * 4; i < n; i += 1024) {
        if (i + 3 < n) {
            int4 e = *(const int4*)(seg + i);
            *(int4*)(sseg + i) = e;
            atomicAdd(&lcnt[e.x & (BNODES - 1)], 1);
            atomicAdd(&lcnt[e.y & (BNODES - 1)], 1);
            atomicAdd(&lcnt[e.z & (BNODES - 1)], 1);
            atomicAdd(&lcnt[e.w & (BNODES - 1)], 1);
        } else {
            for (int j = 0; j < 4 && i + j < n; ++j) {
                int e = seg[i + j];
                sseg[i + j] = e;
                atomicAdd(&lcnt[e & (BNODES - 1)], 1);
            }
        }
    }
    __syncthreads();
    int idx = t * 2;
    int v0 = lcnt[idx], v1 = lcnt[idx + 1];
    int p0 = (v0 + 7) & ~7;           // padded lengths
    int p1 = (v1 + 7) & ~7;
    int s = p0 + p1;
    sums[t] = s;
    __syncthreads();
    for (int off = 1; off < 256; off <<= 1) {
        int x = (t >= off) ? sums[t - off] : 0;
        __syncthreads();
        sums[t] += x;
        __syncthreads();
    }
    int run = sums[t] - s;
    int beg0 = b * SCAP + run;
    int beg1 = beg0 + p0;
    lcur[idx] = beg0;
    lcur[idx + 1] = beg1;
    int node = node0 + idx;
    if (node < N)     { rowse[node]     = make_int2(beg0, beg0 + p0); dis[node]     = rsqrtf((float)(v0 + 1)); }
    if (node + 1 < N) { rowse[node + 1] = make_int2(beg1, beg1 + p1); dis[node + 1] = rsqrtf((float)(v1 + 1)); }
    __syncthreads();
    for (int i = t * 4; i < n; i += 1024) {
        if (i + 3 < n) {
            int4 e = *(const int4*)(sseg + i);
            int q0 = atomicAdd(&lcur[e.x & (BNODES - 1)], 1); ssrc[q0] = e.x >> RSHIFT;
            int q1 = atomicAdd(&lcur[e.y & (BNODES - 1)], 1); ssrc[q1] = e.y >> RSHIFT;
            int q2 = atomicAdd(&lcur[e.z & (BNODES - 1)], 1); ssrc[q2] = e.z >> RSHIFT;
            int q3 = atomicAdd(&lcur[e.w & (BNODES - 1)], 1); ssrc[q3] = e.w >> RSHIFT;
        } else {
            for (int j = 0; j < 4 && i + j < n; ++j) {
                int e = sseg[i + j];
                int q = atomicAdd(&lcur[e & (BNODES - 1)], 1); ssrc[q] = e >> RSHIFT;
            }
        }
    }
    // fill pads with zero-row index N
    for (int k = v0; k < p0; ++k) ssrc[beg0 + k] = N;
    for (int k = v1; k < p1; ++k) ssrc[beg1 + k] = N;
    // ---- degree-class counting sort (lcnt still holds degrees) ----
    __syncthreads();
    if (t < 33) chist[t] = 0;
    __syncthreads();
    int cnt = N - node0; if (cnt > BNODES) cnt = BNODES; if (cnt < 0) cnt = 0;
    for (int i = t; i < cnt; i += 256) {
        int c = (lcnt[i] + 7) >> 3; if (c > 32) c = 32;
        atomicAdd(&chist[c], 1);
    }
    __syncthreads();
    if (t == 0) {
        int acc = 0;
        for (int c = 0; c <= 32; ++c) { int v = chist[c]; chist[c] = acc; acc += v; }
    }
    __syncthreads();
    for (int i = t; i < cnt; i += 256) {
        int c = (lcnt[i] + 7) >> 3; if (c > 32) c = 32;
        int r = atomicAdd(&chist[c], 1);
        nperm[(b << RSHIFT) + r] = node0 + i;
    }
    for (int i = t; i < BNODES; i += 256)
        if (i >= cnt) nperm[(b << RSHIFT) + i] = N;   // sentinel slots
}

// stage W^T as bf16 into LDS: wt[n][k] = bf16(W[k][n]) (validated R10)
__device__ __forceinline__ void stage_wt(const float* __restrict__ W,
                                         ushort_t* __restrict__ wt, int t) {
    const float4* W4 = (const float4*)W;
    for (int i = t; i < 1024; i += 256) {
        float4 w4 = W4[i];
        int k = i >> 4, n0 = (i & 15) * 4;
        wt[(n0 + 0) * FH + k] = rnd_bf16(w4.x);
        wt[(n0 + 1) * FH + k] = rnd_bf16(w4.y);
        wt[(n0 + 2) * FH + k] = rnd_bf16(w4.z);
        wt[(n0 + 3) * FH + k] = rnd_bf16(w4.w);
    }
}

// ---------------- layer-0 GEMM via MFMA: G = bf16((x@W)*dis) -------------
__global__ __launch_bounds__(256) void k_gemm0(const float* __restrict__ x,
                                               const float* __restrict__ W,
                                               const float* __restrict__ dis,
                                               ushort_t* __restrict__ G, int N) {
    __shared__ ushort_t wt[64 * FH];
    int t = threadIdx.x;
    stage_wt(W, wt, t);
    __syncthreads();
    int wv = t >> 6, lane = t & 63;
    int m = lane & 15, quad = lane >> 4;
    int row = blockIdx.x * 64 + wv * 16 + m;
    long rowc = (row < N) ? row : (N - 1);
    float4 f0 = *(const float4*)(x + rowc * D + quad * 8);
    float4 f1 = *(const float4*)(x + rowc * D + quad * 8 + 4);
    float4 f2 = *(const float4*)(x + rowc * D + 32 + quad * 8);
    float4 f3 = *(const float4*)(x + rowc * D + 32 + quad * 8 + 4);
    union { short8 s; uint_t u[4]; } a0, a1;
    a0.u[0] = pk_bf16(f0.x, f0.y); a0.u[1] = pk_bf16(f0.z, f0.w);
    a0.u[2] = pk_bf16(f1.x, f1.y); a0.u[3] = pk_bf16(f1.z, f1.w);
    a1.u[0] = pk_bf16(f2.x, f2.y); a1.u[1] = pk_bf16(f2.z, f2.w);
    a1.u[2] = pk_bf16(f3.x, f3.y); a1.u[3] = pk_bf16(f3.z, f3.w);
    floatx4 acc[4];
    #pragma unroll
    for (int j = 0; j < 4; ++j) {
        short8 b0 = *(short8*)&wt[(j * 16 + m) * FH + quad * 8];
        short8 b1 = *(short8*)&wt[(j * 16 + m) * FH + 32 + quad * 8];
        floatx4 z = {0.f, 0.f, 0.f, 0.f};
        acc[j] = __builtin_amdgcn_mfma_f32_16x16x32_bf16(a0.s, b0, z, 0, 0, 0);
        acc[j] = __builtin_amdgcn_mfma_f32_16x16x32_bf16(a1.s, b1, acc[j], 0, 0, 0);
    }
    int rbase = blockIdx.x * 64 + wv * 16 + quad * 4;
    #pragma unroll
    for (int r = 0; r < 4; ++r) {
        int rr = rbase + r;
        if (rr < N) {
            float sc = dis[rr];
            #pragma unroll
            for (int j = 0; j < 4; ++j)
                G[(size_t)rr * D + j * 16 + m] = rnd_bf16(acc[j][r] * sc);
        }
    }
}

// ---- pull-gather one node with an 8-lane group (R3 pipelined core) ------
__device__ __forceinline__ void gather_node(const ushort_t* __restrict__ G,
                                            const int* __restrict__ ssrc,
                                            int beg, int end, int c8,
                                            int node, float a[8]) {
    #pragma unroll
    for (int j = 0; j < 8; ++j) a[j] = 0.f;
    #define ROW(i) (*(const uint4*)(G + (size_t)(i) * D + c8))
    #define ACC1(u)                                                        \
        {                                                                  \
            a[0] += __uint_as_float(u.x << 16);                            \
            a[1] += __uint_as_float(u.x & 0xffff0000u);                    \
            a[2] += __uint_as_float(u.y << 16);                            \
            a[3] += __uint_as_float(u.y & 0xffff0000u);                    \
            a[4] += __uint_as_float(u.z << 16);                            \
            a[5] += __uint_as_float(u.z & 0xffff0000u);                    \
            a[6] += __uint_as_float(u.w << 16);                            \
            a[7] += __uint_as_float(u.w & 0xffff0000u);                    \
        }
    uint4 su = ROW(node);
    int n8 = (end - beg) >> 3;
    const int4* sp = (const int4*)(ssrc + beg);   // beg is 8-aligned (32B)
    if (n8 > 0) {
        int4 ia = sp[0], ib = sp[1];
        uint4 u0 = ROW(ia.x), u1 = ROW(ia.y), u2 = ROW(ia.z), u3 = ROW(ia.w);
        uint4 u4 = ROW(ib.x), u5 = ROW(ib.y), u6 = ROW(ib.z), u7 = ROW(ib.w);
        if (n8 > 1) { ia = sp[2]; ib = sp[3]; }
        for (int ch = 1; ch < n8; ++ch) {
            uint4 v0 = ROW(ia.x), v1 = ROW(ia.y), v2 = ROW(ia.z), v3 = ROW(ia.w);
            uint4 v4 = ROW(ib.x), v5 = ROW(ib.y), v6 = ROW(ib.z), v7 = ROW(ib.w);
            if (ch + 1 < n8) { ia = sp[2 * ch + 2]; ib = sp[2 * ch + 3]; }
            ACC1(u0); ACC1(u1); ACC1(u2); ACC1(u3);
            ACC1(u4); ACC1(u5); ACC1(u6); ACC1(u7);
            u0 = v0; u1 = v1; u2 = v2; u3 = v3;
            u4 = v4; u5 = v5; u6 = v6; u7 = v7;
        }
        ACC1(u0); ACC1(u1); ACC1(u2); ACC1(u3);
        ACC1(u4); ACC1(u5); ACC1(u6); ACC1(u7);
    }
    ACC1(su);   // self-loop last: its load latency hid under the chunks
    #undef ACC1
    #undef ROW
}

// ---------------- fused agg + next-layer MFMA gemm -----------------------
// Slot -> node via nperm (degree-sorted within bucket). Tile rows are slot-
// indexed; C-write scatters to Gout[node].
__global__ __launch_bounds__(256) void k_fagg(const ushort_t* __restrict__ G,
                                              const float* __restrict__ dis,
                                              const int2* __restrict__ rowse,
                                              const int* __restrict__ ssrc,
                                              const int* __restrict__ nperm,
                                              const float* __restrict__ bias,
                                              const float* __restrict__ W,
                                              ushort_t* __restrict__ Gout,
                                              int N) {
    __shared__ ushort_t hbuf[64 * FH];
    __shared__ ushort_t wt[64 * FH];
    int t = threadIdx.x;
    stage_wt(W, wt, t);
    int wv = t >> 6, lane = t & 63;
    int g = lane >> 3;
    int c8 = (lane & 7) * 8;
    int gbase = blockIdx.x * 64;
    float4 bv0 = *(const float4*)(bias + c8);
    float4 bv1 = *(const float4*)(bias + c8 + 4);
    for (int ii = 0; ii < 2; ++ii) {
        int idx = wv * 16 + ii * 8 + g;
        int node = nperm[gbase + idx];
        if (node < N) {
            int2 se = rowse[node];
            float di = dis[node];
            float a[8];
            gather_node(G, ssrc, se.x, se.y, c8, node, a);
            uint4 p;
            p.x = pk_bf16(a[0] * di + bv0.x, a[1] * di + bv0.y);
            p.y = pk_bf16(a[2] * di + bv0.z, a[3] * di + bv0.w);
            p.z = pk_bf16(a[4] * di + bv1.x, a[5] * di + bv1.y);
            p.w = pk_bf16(a[6] * di + bv1.z, a[7] * di + bv1.w);
            *(uint4*)&hbuf[idx * FH + c8] = p;
        } else {
            uint4 z = {0u, 0u, 0u, 0u};
            *(uint4*)&hbuf[idx * FH + c8] = z;
        }
    }
    __syncthreads();
    // phase 2: MFMA over slot rows (layout validated R10)
    int m = lane & 15, quad = lane >> 4;
    short8 a0 = *(short8*)&hbuf[(wv * 16 + m) * FH + quad * 8];
    short8 a1 = *(short8*)&hbuf[(wv * 16 + m) * FH + 32 + quad * 8];
    floatx4 acc[4];
    #pragma unroll
    for (int j = 0; j < 4; ++j) {
        short8 b0 = *(short8*)&wt[(j * 16 + m) * FH + quad * 8];
        short8 b1 = *(short8*)&wt[(j * 16 + m) * FH + 32 + quad * 8];
        floatx4 z = {0.f, 0.f, 0.f, 0.f};
        acc[j] = __builtin_amdgcn_mfma_f32_16x16x32_bf16(a0, b0, z, 0, 0, 0);
        acc[j] = __builtin_amdgcn_mfma_f32_16x16x32_bf16(a1, b1, acc[j], 0, 0, 0);
    }
    int sbase = wv * 16 + quad * 4;
    int4 nd4 = *(const int4*)&nperm[gbase + sbase];
    int nds[4] = {nd4.x, nd4.y, nd4.z, nd4.w};
    #pragma unroll
    for (int r = 0; r < 4; ++r) {
        int nodeR = nds[r];
        if (nodeR < N) {
            float sc = dis[nodeR];
            #pragma unroll
            for (int j = 0; j < 4; ++j)
                Gout[(size_t)nodeR * D + j * 16 + m] = rnd_bf16(acc[j][r] * sc);
        }
    }
}

// ---------------- final aggregation: out = di*(sum g) + b (fp32) ---------
// One 8-lane group per slot; 32 slots per block; grid covers nb*512 slots.
__global__ __launch_bounds__(256) void k_agg(const ushort_t* __restrict__ G,
                                             const float* __restrict__ dis,
                                             const int2* __restrict__ rowse,
                                             const int* __restrict__ ssrc,
                                             const int* __restrict__ nperm,
                                             const float* __restrict__ bias,
                                             float* __restrict__ out, int N) {
    int t = threadIdx.x;
    int wv = t >> 6, lane = t & 63;
    int g = lane >> 3;
    int c8 = (lane & 7) * 8;
    int slot = blockIdx.x * 32 + wv * 8 + g;
    int node = nperm[slot];
    if (node >= N) return;
    int2 se = rowse[node];
    float di = dis[node];
    float a[8];
    gather_node(G, ssrc, se.x, se.y, c8, node, a);
    float4 bv0 = *(const float4*)(bias + c8);
    float4 bv1 = *(const float4*)(bias + c8 + 4);
    float4 r0, r1;
    r0.x = a[0] * di + bv0.x; r0.y = a[1] * di + bv0.y;
    r0.z = a[2] * di + bv0.z; r0.w = a[3] * di + bv0.w;
    r1.x = a[4] * di + bv1.x; r1.y = a[5] * di + bv1.y;
    r1.z = a[6] * di + bv1.z; r1.w = a[7] * di + bv1.w;
    float4* op = (float4*)(out + (size_t)node * D + c8);
    op[0] = r0;
    op[1] = r1;
}

// ---------------- launch ----------------

extern "C" void kernel_launch(void* const* d_in, const int* in_sizes, int n_in,
                              void* d_out, int out_size, void* d_ws, size_t ws_size,
                              hipStream_t stream) {
    const float* x  = (const float*)d_in[0];
    const int*   ei = (const int*)d_in[1];
    const float* W0 = (const float*)d_in[2];
    const float* b0 = (const float*)d_in[3];
    const float* W1 = (const float*)d_in[4];
    const float* b1 = (const float*)d_in[5];
    const float* W2 = (const float*)d_in[6];
    const float* b2 = (const float*)d_in[7];
    float* out = (float*)d_out;

    const int N = in_sizes[0] / D;
    const int E = in_sizes[1] / 2;
    const int* e_src = ei;
    const int* e_dst = ei + E;

    const int nb = (N + BNODES - 1) >> RSHIFT;   // 196

    // workspace layout ((N+1) rows: row N is the zero pad row)
    size_t rowsz   = (size_t)(N + 1) * D;
    ushort_t* B0   = (ushort_t*)d_ws;                          // (N+1)*D bf16
    ushort_t* B1   = B0 + rowsz;                               // (N+1)*D bf16
    float* dis     = (float*)(B1 + rowsz);                     // N
    int2*  rowse   = (int2*)(dis + N);                         // N
    int*   ssrc    = (int*)(rowse + N);                        // nb*SCAP
    int*   bcur    = ssrc + (size_t)nb * SCAP;                 // MAXB
    int*   nperm   = bcur + MAXB;                              // nb*512
    int*   ebuf    = (int*)d_ws;    // nb*BCAP int = 8 MB, aliases B0 head
                                    // (dead before k_gemm0 writes B0)

    const int gG64 = (N + 63) / 64;              // 1563 (tiles; slots < nb*512)
    const int gAgg = nb * 16;                    // 3136 (covers all nb*512 slots)

    hipMemsetAsync(bcur, 0, MAXB * sizeof(int), stream);
    // zero pad-row N of both G buffers (never written by kernels)
    hipMemsetAsync(B0 + (size_t)N * D, 0, D * sizeof(ushort_t), stream);
    hipMemsetAsync(B1 + (size_t)N * D, 0, D * sizeof(ushort_t), stream);

    k_bucket<<<(E + 2047) / 2048, 256, 0, stream>>>(e_src, e_dst, bcur, ebuf, E, nb);
    k_csr<<<nb, 256, 0, stream>>>(ebuf, bcur, rowse, ssrc, dis, nperm, N, nb);

    // layer 0 gemm (MFMA, bf16 x in-register): x -> B0
    k_gemm0<<<gG64, 256, 0, stream>>>(x, W0, dis, B0, N);
    // fused agg(l0) + gemm(l1): B0 -> B1
    k_fagg<<<gG64, 256, 0, stream>>>(B0, dis, rowse, ssrc, nperm, b0, W1, B1, N);
    // fused agg(l1) + gemm(l2): B1 -> B0
    k_fagg<<<gG64, 256, 0, stream>>>(B1, dis, rowse, ssrc, nperm, b1, W2, B0, N);
    // final agg(l2): B0 -> out (fp32)
    k_agg<<<gAgg, 256, 0, stream>>>(B0, dis, rowse, ssrc, nperm, b2, out, N);
}

// Round 11
// 241.006 us; speedup vs baseline: 1.0538x; 1.0538x over previous
//
#include <hip/hip_runtime.h>
#include <hip/hip_bf16.h>

#define D 64
#define RSHIFT 9             // 512 nodes per dst-bucket
#define BNODES 512
#define MAXB 256             // >= nb = ceil(100000/512) = 196
#define BCAP 10240           // per-bucket edge capacity (mean 8192, sigma ~90)
#define SCAP 14336           // per-bucket PADDED ssrc capacity
#define FH 72                // LDS row stride (bf16): 144B, 4-bank skew per row

typedef unsigned short ushort_t;
typedef unsigned int uint_t;
typedef short short8 __attribute__((ext_vector_type(8)));   // 8 bf16 MFMA frag
typedef float floatx4 __attribute__((ext_vector_type(4)));  // MFMA C/D frag

__device__ inline uint_t pk_bf16(float x, float y) {
    uint_t ux = __float_as_uint(x); ux = ux + 0x7fffu + ((ux >> 16) & 1u);
    uint_t uy = __float_as_uint(y); uy = uy + 0x7fffu + ((uy >> 16) & 1u);
    return (ux >> 16) | (uy & 0xffff0000u);
}
__device__ inline ushort_t rnd_bf16(float x) {
    uint_t u = __float_as_uint(x); u = u + 0x7fffu + ((u >> 16) & 1u);
    return (ushort_t)(u >> 16);
}

// ---------------- stage 1: bucket edges by dst range ----------------
// Packed entry: (src << 9) | (dst & 511). LDS atomics only.
__global__ __launch_bounds__(256) void k_bucket(const int* __restrict__ src,
                                                const int* __restrict__ dst,
                                                int* __restrict__ bcur,
                                                int* __restrict__ ebuf,
                                                int E, int nb) {
    __shared__ int lcnt[MAXB];
    __shared__ int lbase[MAXB];
    int t = threadIdx.x;
    lcnt[t] = 0;
    __syncthreads();
    int base = blockIdx.x * 2048 + t * 8;
    int sv[8], dv[8], sl[8];
    if (base + 7 < E) {
        int4 a0 = *(const int4*)(src + base);
        int4 a1 = *(const int4*)(src + base + 4);
        int4 b0 = *(const int4*)(dst + base);
        int4 b1 = *(const int4*)(dst + base + 4);
        sv[0]=a0.x; sv[1]=a0.y; sv[2]=a0.z; sv[3]=a0.w;
        sv[4]=a1.x; sv[5]=a1.y; sv[6]=a1.z; sv[7]=a1.w;
        dv[0]=b0.x; dv[1]=b0.y; dv[2]=b0.z; dv[3]=b0.w;
        dv[4]=b1.x; dv[5]=b1.y; dv[6]=b1.z; dv[7]=b1.w;
    } else {
        #pragma unroll
        for (int j = 0; j < 8; ++j) {
            dv[j] = (base + j < E) ? dst[base + j] : -1;
            sv[j] = (base + j < E) ? src[base + j] : 0;
        }
    }
    #pragma unroll
    for (int j = 0; j < 8; ++j) {
        if (dv[j] >= 0) {
            int b = dv[j] >> RSHIFT;
            sl[j] = atomicAdd(&lcnt[b], 1);   // LDS atomic only
        }
    }
    __syncthreads();
    if (t < nb) { int c = lcnt[t]; if (c) lbase[t] = atomicAdd(&bcur[t], c); }
    __syncthreads();
    #pragma unroll
    for (int j = 0; j < 8; ++j) {
        if (dv[j] >= 0) {
            int b = dv[j] >> RSHIFT;
            int slot = lbase[b] + sl[j];
            if (slot < BCAP)
                ebuf[(size_t)b * BCAP + slot] = (sv[j] << RSHIFT) | (dv[j] & (BNODES - 1));
        }
    }
}

// ---------------- stage 2: per-bucket CSR build, all atomics in LDS -------
// Fixed per-bucket ssrc region (b*SCAP); per-node segments padded to x8
// (pads -> zero row N) so the gather loop is branch-free with int4 index
// loads. (R10 degree-sort reverted: fagg -3us but nperm indirection +
// heavier csr cost +17us net.)
__global__ __launch_bounds__(256) void k_csr(const int* __restrict__ ebuf,
                                             const int* __restrict__ bcur,
                                             int2* __restrict__ rowse,
                                             int* __restrict__ ssrc,
                                             float* __restrict__ dis,
                                             int N, int nb) {
    __shared__ int sseg[BCAP];        // 40 KB edge stage
    __shared__ int lcnt[BNODES];
    __shared__ int lcur[BNODES];
    __shared__ int sums[256];
    int b = blockIdx.x;
    int t = threadIdx.x;
    int n = bcur[b];
    if (n > BCAP) n = BCAP;
    int node0 = b << RSHIFT;
    #pragma unroll
    for (int i = t; i < BNODES; i += 256) lcnt[i] = 0;
    __syncthreads();
    const int* seg = ebuf + (size_t)b * BCAP;
    for (int i = t * 4; i < n; i += 1024) {
        if (i + 3 < n) {
            int4 e = *(const int4*)(seg + i);
            *(int4*)(sseg + i) = e;
            atomicAdd(&lcnt[e.x & (BNODES - 1)], 1);
            atomicAdd(&lcnt[e.y & (BNODES - 1)], 1);
            atomicAdd(&lcnt[e.z & (BNODES - 1)], 1);
            atomicAdd(&lcnt[e.w & (BNODES - 1)], 1);
        } else {
            for (int j = 0; j < 4 && i + j < n; ++j) {
                int e = seg[i + j];
                sseg[i + j] = e;
                atomicAdd(&lcnt[e & (BNODES - 1)], 1);
            }
        }
    }
    __syncthreads();
    int idx = t * 2;
    int v0 = lcnt[idx], v1 = lcnt[idx + 1];
    int p0 = (v0 + 7) & ~7;           // padded lengths
    int p1 = (v1 + 7) & ~7;
    int s = p0 + p1;
    sums[t] = s;
    __syncthreads();
    for (int off = 1; off < 256; off <<= 1) {
        int x = (t >= off) ? sums[t - off] : 0;
        __syncthreads();
        sums[t] += x;
        __syncthreads();
    }
    int run = sums[t] - s;
    int beg0 = b * SCAP + run;
    int beg1 = beg0 + p0;
    lcur[idx] = beg0;
    lcur[idx + 1] = beg1;
    int node = node0 + idx;
    if (node < N)     { rowse[node]     = make_int2(beg0, beg0 + p0); dis[node]     = rsqrtf((float)(v0 + 1)); }
    if (node + 1 < N) { rowse[node + 1] = make_int2(beg1, beg1 + p1); dis[node + 1] = rsqrtf((float)(v1 + 1)); }
    __syncthreads();
    for (int i = t * 4; i < n; i += 1024) {
        if (i + 3 < n) {
            int4 e = *(const int4*)(sseg + i);
            int q0 = atomicAdd(&lcur[e.x & (BNODES - 1)], 1); ssrc[q0] = e.x >> RSHIFT;
            int q1 = atomicAdd(&lcur[e.y & (BNODES - 1)], 1); ssrc[q1] = e.y >> RSHIFT;
            int q2 = atomicAdd(&lcur[e.z & (BNODES - 1)], 1); ssrc[q2] = e.z >> RSHIFT;
            int q3 = atomicAdd(&lcur[e.w & (BNODES - 1)], 1); ssrc[q3] = e.w >> RSHIFT;
        } else {
            for (int j = 0; j < 4 && i + j < n; ++j) {
                int e = sseg[i + j];
                int q = atomicAdd(&lcur[e & (BNODES - 1)], 1); ssrc[q] = e >> RSHIFT;
            }
        }
    }
    // fill pads with zero-row index N
    for (int k = v0; k < p0; ++k) ssrc[beg0 + k] = N;
    for (int k = v1; k < p1; ++k) ssrc[beg1 + k] = N;
}

// stage W^T as bf16 into LDS: wt[n][k] = bf16(W[k][n]) (validated R10)
__device__ __forceinline__ void stage_wt(const float* __restrict__ W,
                                         ushort_t* __restrict__ wt, int t) {
    const float4* W4 = (const float4*)W;
    for (int i = t; i < 1024; i += 256) {
        float4 w4 = W4[i];
        int k = i >> 4, n0 = (i & 15) * 4;
        wt[(n0 + 0) * FH + k] = rnd_bf16(w4.x);
        wt[(n0 + 1) * FH + k] = rnd_bf16(w4.y);
        wt[(n0 + 2) * FH + k] = rnd_bf16(w4.z);
        wt[(n0 + 3) * FH + k] = rnd_bf16(w4.w);
    }
}

// ---------------- layer-0 GEMM via MFMA: G = bf16((x@W)*dis) -------------
__global__ __launch_bounds__(256) void k_gemm0(const float* __restrict__ x,
                                               const float* __restrict__ W,
                                               const float* __restrict__ dis,
                                               ushort_t* __restrict__ G, int N) {
    __shared__ ushort_t wt[64 * FH];
    int t = threadIdx.x;
    stage_wt(W, wt, t);
    __syncthreads();
    int wv = t >> 6, lane = t & 63;
    int m = lane & 15, quad = lane >> 4;
    int row = blockIdx.x * 64 + wv * 16 + m;
    long rowc = (row < N) ? row : (N - 1);
    float4 f0 = *(const float4*)(x + rowc * D + quad * 8);
    float4 f1 = *(const float4*)(x + rowc * D + quad * 8 + 4);
    float4 f2 = *(const float4*)(x + rowc * D + 32 + quad * 8);
    float4 f3 = *(const float4*)(x + rowc * D + 32 + quad * 8 + 4);
    union { short8 s; uint_t u[4]; } a0, a1;
    a0.u[0] = pk_bf16(f0.x, f0.y); a0.u[1] = pk_bf16(f0.z, f0.w);
    a0.u[2] = pk_bf16(f1.x, f1.y); a0.u[3] = pk_bf16(f1.z, f1.w);
    a1.u[0] = pk_bf16(f2.x, f2.y); a1.u[1] = pk_bf16(f2.z, f2.w);
    a1.u[2] = pk_bf16(f3.x, f3.y); a1.u[3] = pk_bf16(f3.z, f3.w);
    floatx4 acc[4];
    #pragma unroll
    for (int j = 0; j < 4; ++j) {
        short8 b0 = *(short8*)&wt[(j * 16 + m) * FH + quad * 8];
        short8 b1 = *(short8*)&wt[(j * 16 + m) * FH + 32 + quad * 8];
        floatx4 z = {0.f, 0.f, 0.f, 0.f};
        acc[j] = __builtin_amdgcn_mfma_f32_16x16x32_bf16(a0.s, b0, z, 0, 0, 0);
        acc[j] = __builtin_amdgcn_mfma_f32_16x16x32_bf16(a1.s, b1, acc[j], 0, 0, 0);
    }
    int rbase = blockIdx.x * 64 + wv * 16 + quad * 4;
    #pragma unroll
    for (int r = 0; r < 4; ++r) {
        int rr = rbase + r;
        if (rr < N) {
            float sc = dis[rr];
            #pragma unroll
            for (int j = 0; j < 4; ++j)
                G[(size_t)rr * D + j * 16 + m] = rnd_bf16(acc[j][r] * sc);
        }
    }
}

// ---- pull-gather one node with an 8-lane group (R3 pipelined core) ------
// Software-pipelined: chunk c+1's 8 row-loads are issued BEFORE chunk c's
// ACCUM. Segment length is a multiple of 8 (pads -> zero row N).
__device__ __forceinline__ void gather_node(const ushort_t* __restrict__ G,
                                            const int* __restrict__ ssrc,
                                            int beg, int end, int c8,
                                            int node, float a[8]) {
    #pragma unroll
    for (int j = 0; j < 8; ++j) a[j] = 0.f;
    #define ROW(i) (*(const uint4*)(G + (size_t)(i) * D + c8))
    #define ACC1(u)                                                        \
        {                                                                  \
            a[0] += __uint_as_float(u.x << 16);                            \
            a[1] += __uint_as_float(u.x & 0xffff0000u);                    \
            a[2] += __uint_as_float(u.y << 16);                            \
            a[3] += __uint_as_float(u.y & 0xffff0000u);                    \
            a[4] += __uint_as_float(u.z << 16);                            \
            a[5] += __uint_as_float(u.z & 0xffff0000u);                    \
            a[6] += __uint_as_float(u.w << 16);                            \
            a[7] += __uint_as_float(u.w & 0xffff0000u);                    \
        }
    uint4 su = ROW(node);
    int n8 = (end - beg) >> 3;
    const int4* sp = (const int4*)(ssrc + beg);   // beg is 8-aligned (32B)
    if (n8 > 0) {
        int4 ia = sp[0], ib = sp[1];
        uint4 u0 = ROW(ia.x), u1 = ROW(ia.y), u2 = ROW(ia.z), u3 = ROW(ia.w);
        uint4 u4 = ROW(ib.x), u5 = ROW(ib.y), u6 = ROW(ib.z), u7 = ROW(ib.w);
        if (n8 > 1) { ia = sp[2]; ib = sp[3]; }
        for (int ch = 1; ch < n8; ++ch) {
            uint4 v0 = ROW(ia.x), v1 = ROW(ia.y), v2 = ROW(ia.z), v3 = ROW(ia.w);
            uint4 v4 = ROW(ib.x), v5 = ROW(ib.y), v6 = ROW(ib.z), v7 = ROW(ib.w);
            if (ch + 1 < n8) { ia = sp[2 * ch + 2]; ib = sp[2 * ch + 3]; }
            ACC1(u0); ACC1(u1); ACC1(u2); ACC1(u3);
            ACC1(u4); ACC1(u5); ACC1(u6); ACC1(u7);
            u0 = v0; u1 = v1; u2 = v2; u3 = v3;
            u4 = v4; u5 = v5; u6 = v6; u7 = v7;
        }
        ACC1(u0); ACC1(u1); ACC1(u2); ACC1(u3);
        ACC1(u4); ACC1(u5); ACC1(u6); ACC1(u7);
    }
    ACC1(su);   // self-loop last: its load latency hid under the chunks
    #undef ACC1
    #undef ROW
}

// ---------------- fused agg + next-layer MFMA gemm -----------------------
// Block = 64 nodes, 4 waves x 8 groups x 2 serial nodes (R3 structure —
// best measured, 239.8us).
__global__ __launch_bounds__(256) void k_fagg(const ushort_t* __restrict__ G,
                                              const float* __restrict__ dis,
                                              const int2* __restrict__ rowse,
                                              const int* __restrict__ ssrc,
                                              const float* __restrict__ bias,
                                              const float* __restrict__ W,
                                              ushort_t* __restrict__ Gout,
                                              int N) {
    __shared__ ushort_t hbuf[64 * FH];
    __shared__ ushort_t wt[64 * FH];
    int t = threadIdx.x;
    stage_wt(W, wt, t);
    int wv = t >> 6, lane = t & 63;
    int g = lane >> 3;
    int c8 = (lane & 7) * 8;
    int gbase = blockIdx.x * 64;
    float4 bv0 = *(const float4*)(bias + c8);
    float4 bv1 = *(const float4*)(bias + c8 + 4);
    for (int ii = 0; ii < 2; ++ii) {
        int idx = wv * 16 + ii * 8 + g;
        int node = gbase + idx;
        if (node < N) {
            int2 se = rowse[node];
            float di = dis[node];
            float a[8];
            gather_node(G, ssrc, se.x, se.y, c8, node, a);
            uint4 p;
            p.x = pk_bf16(a[0] * di + bv0.x, a[1] * di + bv0.y);
            p.y = pk_bf16(a[2] * di + bv0.z, a[3] * di + bv0.w);
            p.z = pk_bf16(a[4] * di + bv1.x, a[5] * di + bv1.y);
            p.w = pk_bf16(a[6] * di + bv1.z, a[7] * di + bv1.w);
            *(uint4*)&hbuf[idx * FH + c8] = p;
        }
    }
    __syncthreads();
    // phase 2: MFMA (layout validated R10)
    int m = lane & 15, quad = lane >> 4;
    short8 a0 = *(short8*)&hbuf[(wv * 16 + m) * FH + quad * 8];
    short8 a1 = *(short8*)&hbuf[(wv * 16 + m) * FH + 32 + quad * 8];
    floatx4 acc[4];
    #pragma unroll
    for (int j = 0; j < 4; ++j) {
        short8 b0 = *(short8*)&wt[(j * 16 + m) * FH + quad * 8];
        short8 b1 = *(short8*)&wt[(j * 16 + m) * FH + 32 + quad * 8];
        floatx4 z = {0.f, 0.f, 0.f, 0.f};
        acc[j] = __builtin_amdgcn_mfma_f32_16x16x32_bf16(a0, b0, z, 0, 0, 0);
        acc[j] = __builtin_amdgcn_mfma_f32_16x16x32_bf16(a1, b1, acc[j], 0, 0, 0);
    }
    int rbase = gbase + wv * 16 + quad * 4;
    #pragma unroll
    for (int r = 0; r < 4; ++r) {
        int row = rbase + r;
        if (row < N) {
            float sc = dis[row];
            #pragma unroll
            for (int j = 0; j < 4; ++j)
                Gout[(size_t)row * D + j * 16 + m] = rnd_bf16(acc[j][r] * sc);
        }
    }
}

// ---------------- final aggregation: out = di*(sum g) + b (fp32) ---------
// One 8-lane group per node; 32 nodes per block.
__global__ __launch_bounds__(256) void k_agg(const ushort_t* __restrict__ G,
                                             const float* __restrict__ dis,
                                             const int2* __restrict__ rowse,
                                             const int* __restrict__ ssrc,
                                             const float* __restrict__ bias,
                                             float* __restrict__ out, int N) {
    int t = threadIdx.x;
    int wv = t >> 6, lane = t & 63;
    int g = lane >> 3;
    int c8 = (lane & 7) * 8;
    int node = blockIdx.x * 32 + wv * 8 + g;
    if (node >= N) return;
    int2 se = rowse[node];
    float di = dis[node];
    float a[8];
    gather_node(G, ssrc, se.x, se.y, c8, node, a);
    float4 bv0 = *(const float4*)(bias + c8);
    float4 bv1 = *(const float4*)(bias + c8 + 4);
    float4 r0, r1;
    r0.x = a[0] * di + bv0.x; r0.y = a[1] * di + bv0.y;
    r0.z = a[2] * di + bv0.z; r0.w = a[3] * di + bv0.w;
    r1.x = a[4] * di + bv1.x; r1.y = a[5] * di + bv1.y;
    r1.z = a[6] * di + bv1.z; r1.w = a[7] * di + bv1.w;
    float4* op = (float4*)(out + (size_t)node * D + c8);
    op[0] = r0;
    op[1] = r1;
}

// ---------------- launch ----------------

extern "C" void kernel_launch(void* const* d_in, const int* in_sizes, int n_in,
                              void* d_out, int out_size, void* d_ws, size_t ws_size,
                              hipStream_t stream) {
    const float* x  = (const float*)d_in[0];
    const int*   ei = (const int*)d_in[1];
    const float* W0 = (const float*)d_in[2];
    const float* b0 = (const float*)d_in[3];
    const float* W1 = (const float*)d_in[4];
    const float* b1 = (const float*)d_in[5];
    const float* W2 = (const float*)d_in[6];
    const float* b2 = (const float*)d_in[7];
    float* out = (float*)d_out;

    const int N = in_sizes[0] / D;
    const int E = in_sizes[1] / 2;
    const int* e_src = ei;
    const int* e_dst = ei + E;

    const int nb = (N + BNODES - 1) >> RSHIFT;   // 196

    // workspace layout ((N+1) rows: row N is the zero pad row)
    size_t rowsz   = (size_t)(N + 1) * D;
    ushort_t* B0   = (ushort_t*)d_ws;                          // (N+1)*D bf16
    ushort_t* B1   = B0 + rowsz;                               // (N+1)*D bf16
    float* dis     = (float*)(B1 + rowsz);                     // N
    int2*  rowse   = (int2*)(dis + N);                         // N
    int*   ssrc    = (int*)(rowse + N);                        // nb*SCAP
    int*   bcur    = ssrc + (size_t)nb * SCAP;                 // MAXB
    int*   ebuf    = (int*)d_ws;    // nb*BCAP int = 8 MB, aliases B0 head
                                    // (dead before k_gemm0 writes B0)

    const int gG64 = (N + 63) / 64;              // 1563
    const int gAgg = (N + 31) / 32;              // 3125

    hipMemsetAsync(bcur, 0, MAXB * sizeof(int), stream);
    // zero pad-row N of both G buffers (never written by kernels)
    hipMemsetAsync(B0 + (size_t)N * D, 0, D * sizeof(ushort_t), stream);
    hipMemsetAsync(B1 + (size_t)N * D, 0, D * sizeof(ushort_t), stream);

    k_bucket<<<(E + 2047) / 2048, 256, 0, stream>>>(e_src, e_dst, bcur, ebuf, E, nb);
    k_csr<<<nb, 256, 0, stream>>>(ebuf, bcur, rowse, ssrc, dis, N, nb);

    // layer 0 gemm (MFMA, bf16 x in-register): x -> B0
    k_gemm0<<<gG64, 256, 0, stream>>>(x, W0, dis, B0, N);
    // fused agg(l0) + gemm(l1): B0 -> B1
    k_fagg<<<gG64, 256, 0, stream>>>(B0, dis, rowse, ssrc, b0, W1, B1, N);
    // fused agg(l1) + gemm(l2): B1 -> B0
    k_fagg<<<gG64, 256, 0, stream>>>(B1, dis, rowse, ssrc, b1, W2, B0, N);
    // final agg(l2): B0 -> out (fp32)
    k_agg<<<gAgg, 256, 0, stream>>>(B0, dis, rowse, ssrc, b2, out, N);
}